// Round 5
// baseline (584.888 us; speedup 1.0000x reference)
//
#include <hip/hip_runtime.h>

#define N_ATOMS 100000
#define N_PAIRS 3200000
#define N_PROP 16
#define N_BASIS 10
#define W 16
#define NT (N_PAIRS / 16)     // 200000 16-pair tiles
#define NSUP (NT / 2)         // 100000 2-tile supers
#define SCAN_BLK 1024
#define NB ((N_ATOMS + SCAN_BLK - 1) / SCAN_BLK)   // 98
#define SC 2.88539008177792681f   // 2*log2(e), folded into weights

typedef short  s16x8 __attribute__((ext_vector_type(8)));
typedef float  f32x4 __attribute__((ext_vector_type(4)));

// tanh with pre-scaled input: y = SC*x  ->  tanh(x) = 1 - 2/(exp2(y)+1)
__device__ __forceinline__ float tanh_pre(float y) {
    float e = __builtin_amdgcn_exp2f(y);
    return 1.0f - 2.0f * __builtin_amdgcn_rcpf(e + 1.0f);
}
// classic tanh for the f32 VALU kernels
__device__ __forceinline__ float fast_tanh(float x) {
    float e = __builtin_amdgcn_exp2f(x * SC);
    return 1.0f - 2.0f * __builtin_amdgcn_rcpf(e + 1.0f);
}
__device__ __forceinline__ unsigned short bf16r(float f) {
    union { float f; unsigned u; } v; v.f = f;
    unsigned r = v.u + 0x7FFFu + ((v.u >> 16) & 1u);
    return (unsigned short)(r >> 16);
}
__device__ __forceinline__ float bf16f(unsigned short h) {
    union { unsigned u; float f; } v; v.u = ((unsigned)h) << 16; return v.f;
}
__device__ __forceinline__ unsigned cvt_pk_bf16(float a, float b) {
    unsigned r;
    asm("v_cvt_pk_bf16_f32 %0, %1, %2" : "=v"(r) : "v"(a), "v"(b));
    return r;   // low16 = bf16(a), high16 = bf16(b), RTNE
}
__device__ __forceinline__ float bitf(unsigned u) {
    union { unsigned u; float f; } v; v.u = u; return v.f;
}

// ---------------- pp_pre: emits bf16 hi/lo split of p1_in
__global__ __launch_bounds__(256) void k_pp_pre(
    const float* __restrict__ p1,
    const float* __restrict__ W0, const float* __restrict__ b0,
    const float* __restrict__ W1, const float* __restrict__ b1,
    unsigned short* __restrict__ p1h, unsigned short* __restrict__ p1l)
{
    int a = blockIdx.x * 256 + threadIdx.x;
    if (a >= N_ATOMS) return;
    const float4* src = reinterpret_cast<const float4*>(p1 + (size_t)a * N_PROP);
    float4 v0 = src[0], v1 = src[1], v2 = src[2], v3 = src[3];
    float x[N_PROP] = {v0.x,v0.y,v0.z,v0.w, v1.x,v1.y,v1.z,v1.w,
                       v2.x,v2.y,v2.z,v2.w, v3.x,v3.y,v3.z,v3.w};
    float h[W];
#pragma unroll
    for (int c = 0; c < W; ++c) h[c] = b0[c];
#pragma unroll
    for (int k = 0; k < N_PROP; ++k)
#pragma unroll
        for (int c = 0; c < W; ++c) h[c] += x[k] * W0[k*W + c];
#pragma unroll
    for (int c = 0; c < W; ++c) h[c] = fast_tanh(h[c]);
    float y[W];
#pragma unroll
    for (int c = 0; c < W; ++c) y[c] = b1[c];
#pragma unroll
    for (int k = 0; k < W; ++k)
#pragma unroll
        for (int c = 0; c < W; ++c) y[c] += h[k] * W1[k*W + c];
    union { unsigned short u[8]; s16x8 v; } hi0, hi1, lo0, lo1;
#pragma unroll
    for (int c = 0; c < W; ++c) {
        float t = fast_tanh(y[c]);
        unsigned short hb = bf16r(t);
        unsigned short lb = bf16r(t - bf16f(hb));
        if (c < 8) { hi0.u[c] = hb; lo0.u[c] = lb; }
        else       { hi1.u[c-8] = hb; lo1.u[c-8] = lb; }
    }
    s16x8* dh = reinterpret_cast<s16x8*>(p1h + (size_t)a * W);
    s16x8* dl = reinterpret_cast<s16x8*>(p1l + (size_t)a * W);
    dh[0] = hi0.v; dh[1] = hi1.v;
    dl[0] = lo0.v; dl[1] = lo1.v;
}

// C-layout x[i] = value for ch 4g+i, pair r at lane (r,g)  ->  B-frag (k=8g'+j).
// hi/lo split version. Garbage at g'>=2 (beyond u[0] of g'==2) is killed by zero A-rows.
__device__ __forceinline__ void make_B_hilo(const float x[4], int idxA, int idxB,
                                            int g, bool augment, s16x8& Bh, s16x8& Bl)
{
    unsigned w0h = cvt_pk_bf16(x[0], x[1]);
    unsigned w1h = cvt_pk_bf16(x[2], x[3]);
    float f0 = bitf(w0h << 16), f1 = bitf(w0h & 0xFFFF0000u);
    float f2 = bitf(w1h << 16), f3 = bitf(w1h & 0xFFFF0000u);
    unsigned w0l = cvt_pk_bf16(x[0] - f0, x[1] - f1);
    unsigned w1l = cvt_pk_bf16(x[2] - f2, x[3] - f3);
    union { unsigned u[4]; s16x8 v; } H, L;
    H.u[0] = (unsigned)__shfl((int)w0h, idxA); H.u[1] = (unsigned)__shfl((int)w1h, idxA);
    H.u[2] = (unsigned)__shfl((int)w0h, idxB); H.u[3] = (unsigned)__shfl((int)w1h, idxB);
    L.u[0] = (unsigned)__shfl((int)w0l, idxA); L.u[1] = (unsigned)__shfl((int)w1l, idxA);
    L.u[2] = (unsigned)__shfl((int)w0l, idxB); L.u[3] = (unsigned)__shfl((int)w1l, idxB);
    if (augment && g == 2) { H.u[0] = 0x3F80u; L.u[0] = 0u; }   // k=16 bias row = 1.0
    Bh = H.v; Bl = L.v;
}

// hi-only variant
__device__ __forceinline__ s16x8 make_B_hi(const float x[4], int idxA, int idxB)
{
    unsigned w0 = cvt_pk_bf16(x[0], x[1]);
    unsigned w1 = cvt_pk_bf16(x[2], x[3]);
    union { unsigned u[4]; s16x8 v; } H;
    H.u[0] = (unsigned)__shfl((int)w0, idxA); H.u[1] = (unsigned)__shfl((int)w1, idxA);
    H.u[2] = (unsigned)__shfl((int)w0, idxB); H.u[3] = (unsigned)__shfl((int)w1, idxB);
    return H.v;
}

// ---------------- pair kernel: 2 tiles (32 pairs) per wave iteration
// pi1 packing: tile t, A-row rr -> ch = 4*(rr>>2)+(t&3), bp = 4*(t>>2)+(rr&3)
// => lane (r,g) C-reg i accumulates ch 4g+(t&3), bp 4*(t>>2)+i  (vloc[m] = ch 4g+m)
template<int USE_RANK>
__global__ __launch_bounds__(256) void k_pair_mfma(
    const int*   __restrict__ ind2,
    const float* __restrict__ basis,
    const unsigned short* __restrict__ p1h,
    const unsigned short* __restrict__ p1l,
    const float* __restrict__ Wpi0, const float* __restrict__ bpi0,
    const float* __restrict__ Wpi1, const float* __restrict__ bpi1,
    const float* __restrict__ Wii0, const float* __restrict__ Wii1,
    float* __restrict__ i_pair_out,
    const unsigned* __restrict__ starts,
    const unsigned* __restrict__ rank,
    unsigned* __restrict__ cursor,
    float* __restrict__ svals)
{
    __shared__ s16x8 a2_lds[12][4][16];   // [t][g][r], 16B entries, linear across lanes

    const int lane = threadIdx.x & 63;
    const int w    = threadIdx.x >> 6;
    const int r    = lane & 15;
    const int g    = lane >> 4;
    const int idxA = (r + 32*g) & 63;     // source lane (r, 2g)
    const int idxB = (idxA + 16) & 63;    // source lane (r, 2g+1)

    // fill a2 LDS (768 entries, 3 per thread), weights pre-scaled by SC
    for (int e = threadIdx.x; e < 768; e += 256) {
        int t  = e >> 6;
        int rr = (e >> 2) & 15;
        int gg = e & 3;
        int ch = 4*(rr >> 2) + (t & 3);
        int bp = 4*(t >> 2) + (rr & 3);
        s16x8 val;
#pragma unroll
        for (int j = 0; j < 8; ++j) {
            int k = 8*gg + j;
            float wv = 0.0f;
            if (bp < N_BASIS) {
                if (k < W)       wv = Wpi1[k*(W*N_BASIS) + ch*N_BASIS + bp];
                else if (k == W) wv = bpi1[ch*N_BASIS + bp];
            }
            val[j] = (short)bf16r(SC * wv);
        }
        a2_lds[t][gg][rr] = val;
    }

    s16x8 a1, a3, a4;
#pragma unroll
    for (int j = 0; j < 8; ++j) {
        int k = 8*g + j;
        a1[j] = (short)bf16r(SC * Wpi0[k*W + r]);
        a3[j] = (short)(k < W ? bf16r(SC * Wii0[k*W + r]) : 0);
        a4[j] = (short)(k < W ? bf16r(SC * Wii1[k*W + r]) : 0);
    }
    float b0v[4];
#pragma unroll
    for (int i = 0; i < 4; ++i) b0v[i] = SC * bpi0[4*g + i];

    __syncthreads();

    for (int sup = blockIdx.x * 4 + w; sup < NSUP; sup += gridDim.x * 4) {
        const int pA = sup * 32 + r;
        const int pB = pA + 16;
        int2 ijA = reinterpret_cast<const int2*>(ind2)[pA];
        int2 ijB = reinterpret_cast<const int2*>(ind2)[pB];
        int atomA = (g < 2) ? ijA.x : ijA.y;
        int atomB = (g < 2) ? ijB.x : ijB.y;

        const s16x8 B1hA = *reinterpret_cast<const s16x8*>(p1h + (size_t)atomA * W + (g & 1) * 8);
        const s16x8 B1lA = *reinterpret_cast<const s16x8*>(p1l + (size_t)atomA * W + (g & 1) * 8);
        const s16x8 B1hB = *reinterpret_cast<const s16x8*>(p1h + (size_t)atomB * W + (g & 1) * 8);
        const s16x8 B1lB = *reinterpret_cast<const s16x8*>(p1l + (size_t)atomB * W + (g & 1) * 8);

        float basA[12], basB[12];
        {
            const float2* bbA = reinterpret_cast<const float2*>(basis + (size_t)pA * N_BASIS);
            const float2* bbB = reinterpret_cast<const float2*>(basis + (size_t)pB * N_BASIS);
#pragma unroll
            for (int q = 0; q < 5; ++q) {
                float2 tA = bbA[q]; basA[2*q] = tA.x; basA[2*q+1] = tA.y;
                float2 tB = bbB[q]; basB[2*q] = tB.x; basB[2*q+1] = tB.y;
            }
            basA[10] = basA[11] = 0.0f;
            basB[10] = basB[11] = 0.0f;
        }

        // ---- pi0 (K=32), hi/lo
        f32x4 accA = {0.f,0.f,0.f,0.f}, accB = {0.f,0.f,0.f,0.f};
        accA = __builtin_amdgcn_mfma_f32_16x16x32_bf16(a1, B1hA, accA, 0, 0, 0);
        accB = __builtin_amdgcn_mfma_f32_16x16x32_bf16(a1, B1hB, accB, 0, 0, 0);
        accA = __builtin_amdgcn_mfma_f32_16x16x32_bf16(a1, B1lA, accA, 0, 0, 0);
        accB = __builtin_amdgcn_mfma_f32_16x16x32_bf16(a1, B1lB, accB, 0, 0, 0);
        float h0A[4], h0B[4];
#pragma unroll
        for (int i = 0; i < 4; ++i) {
            h0A[i] = tanh_pre(accA[i] + b0v[i]);
            h0B[i] = tanh_pre(accB[i] + b0v[i]);
        }

        s16x8 B2hA, B2lA, B2hB, B2lB;
        make_B_hilo(h0A, idxA, idxB, g, true, B2hA, B2lA);
        make_B_hilo(h0B, idxA, idxB, g, true, B2hB, B2lB);

        // ---- pi1: 12 tiles, in-register basis contraction
        float vlA[4] = {0.f,0.f,0.f,0.f}, vlB[4] = {0.f,0.f,0.f,0.f};
#pragma unroll
        for (int t = 0; t < 12; ++t) {
            s16x8 af = a2_lds[t][g][r];
            f32x4 zA = {0.f,0.f,0.f,0.f}, zB = {0.f,0.f,0.f,0.f};
            zA = __builtin_amdgcn_mfma_f32_16x16x32_bf16(af, B2hA, zA, 0, 0, 0);
            zB = __builtin_amdgcn_mfma_f32_16x16x32_bf16(af, B2hB, zB, 0, 0, 0);
            zA = __builtin_amdgcn_mfma_f32_16x16x32_bf16(af, B2lA, zA, 0, 0, 0);
            zB = __builtin_amdgcn_mfma_f32_16x16x32_bf16(af, B2lB, zB, 0, 0, 0);
#pragma unroll
            for (int i = 0; i < 4; ++i) {
                const int bi = 4*(t >> 2) + i;
                const int m  = t & 3;
                vlA[m] += tanh_pre(zA[i]) * basA[bi];
                vlB[m] += tanh_pre(zB[i]) * basB[bi];
            }
        }

        // ---- ii0 (garbage at g>=2 killed by zero A-rows of a3)
        s16x8 B3hA = make_B_hi(vlA, idxA, idxB);
        s16x8 B3hB = make_B_hi(vlB, idxA, idxB);
        f32x4 uaA = {0.f,0.f,0.f,0.f}, uaB = {0.f,0.f,0.f,0.f};
        uaA = __builtin_amdgcn_mfma_f32_16x16x32_bf16(a3, B3hA, uaA, 0, 0, 0);
        uaB = __builtin_amdgcn_mfma_f32_16x16x32_bf16(a3, B3hB, uaB, 0, 0, 0);
        float tuA[4], tuB[4];
#pragma unroll
        for (int i = 0; i < 4; ++i) {
            tuA[i] = tanh_pre(uaA[i]);
            tuB[i] = tanh_pre(uaB[i]);
        }

        // ---- ii1
        s16x8 B4hA = make_B_hi(tuA, idxA, idxB);
        s16x8 B4hB = make_B_hi(tuB, idxA, idxB);
        f32x4 waA = {0.f,0.f,0.f,0.f}, waB = {0.f,0.f,0.f,0.f};
        waA = __builtin_amdgcn_mfma_f32_16x16x32_bf16(a4, B4hA, waA, 0, 0, 0);
        waB = __builtin_amdgcn_mfma_f32_16x16x32_bf16(a4, B4hB, waB, 0, 0, 0);
        float4 outA = make_float4(tanh_pre(waA[0]), tanh_pre(waA[1]),
                                  tanh_pre(waA[2]), tanh_pre(waA[3]));
        float4 outB = make_float4(tanh_pre(waB[0]), tanh_pre(waB[1]),
                                  tanh_pre(waB[2]), tanh_pre(waB[3]));

        *reinterpret_cast<float4*>(i_pair_out + (size_t)pA * W + 4*g) = outA;
        *reinterpret_cast<float4*>(i_pair_out + (size_t)pB * W + 4*g) = outB;

        unsigned posA, posB;
        if (USE_RANK) {
            posA = starts[ijA.x] + rank[pA];
            posB = starts[ijB.x] + rank[pB];
        } else {
            unsigned ppA = 0, ppB = 0;
            if (g == 0) {
                ppA = atomicAdd(&cursor[ijA.x], 1u);
                ppB = atomicAdd(&cursor[ijB.x], 1u);
            }
            posA = (unsigned)__shfl((int)ppA, r);
            posB = (unsigned)__shfl((int)ppB, r);
        }
        *reinterpret_cast<float4*>(svals + (size_t)posA * W + 4*g) = outA;
        *reinterpret_cast<float4*>(svals + (size_t)posB * W + 4*g) = outB;
    }
}

// ---------------- IP pipeline
__global__ __launch_bounds__(256) void k_count(const int* __restrict__ ind2,
                                               unsigned* __restrict__ counts,
                                               unsigned* __restrict__ rank)
{
    int p = blockIdx.x * 256 + threadIdx.x;
    if (p >= N_PAIRS) return;
    rank[p] = atomicAdd(&counts[ind2[2*p]], 1u);
}

__global__ __launch_bounds__(SCAN_BLK) void k_scanA(const unsigned* __restrict__ counts,
                                                    unsigned* __restrict__ starts,
                                                    unsigned* __restrict__ bsum)
{
    __shared__ unsigned sc[SCAN_BLK];
    int a = blockIdx.x * SCAN_BLK + threadIdx.x;
    unsigned c = (a < N_ATOMS) ? counts[a] : 0u;
    sc[threadIdx.x] = c;
    __syncthreads();
    for (int off = 1; off < SCAN_BLK; off <<= 1) {
        unsigned v = sc[threadIdx.x];
        unsigned add = (threadIdx.x >= off) ? sc[threadIdx.x - off] : 0u;
        __syncthreads();
        sc[threadIdx.x] = v + add;
        __syncthreads();
    }
    if (a < N_ATOMS) starts[a] = sc[threadIdx.x] - c;
    if (threadIdx.x == SCAN_BLK - 1) bsum[blockIdx.x] = sc[SCAN_BLK - 1];
}

__global__ __launch_bounds__(128) void k_scanB(const unsigned* __restrict__ bsum,
                                               unsigned* __restrict__ boff)
{
    __shared__ unsigned s[128];
    int t = threadIdx.x;
    unsigned v = (t < NB) ? bsum[t] : 0u;
    s[t] = v;
    __syncthreads();
    for (int off = 1; off < 128; off <<= 1) {
        unsigned x = s[t];
        unsigned add = (t >= off) ? s[t - off] : 0u;
        __syncthreads();
        s[t] = x + add;
        __syncthreads();
    }
    if (t < NB) boff[t] = s[t] - v;
}

__global__ __launch_bounds__(SCAN_BLK) void k_scanC(unsigned* __restrict__ starts,
                                                    const unsigned* __restrict__ boff,
                                                    unsigned* __restrict__ cursor)
{
    int a = blockIdx.x * SCAN_BLK + threadIdx.x;
    if (a >= N_ATOMS) return;
    unsigned s = starts[a] + boff[blockIdx.x];
    starts[a] = s;
    cursor[a] = s;
}

__global__ __launch_bounds__(256) void k_reduce_stream(const unsigned* __restrict__ starts,
                                                       const unsigned* __restrict__ counts,
                                                       const float* __restrict__ svals,
                                                       float* __restrict__ p_sum)
{
    int a = blockIdx.x * 4 + (threadIdx.x >> 6);
    if (a >= N_ATOMS) return;
    int lane = threadIdx.x & 63;
    int c = lane & 15, q = lane >> 4;
    unsigned n = counts[a], st = starts[a];
    float acc = 0.0f;
    for (unsigned k = q; k < n; k += 4)
        acc += svals[(size_t)(st + k) * W + c];
    acc += __shfl_xor(acc, 16);
    acc += __shfl_xor(acc, 32);
    if (q == 0) p_sum[(size_t)a * W + c] = acc;
}

// ---------------- pp_post
__global__ __launch_bounds__(256) void k_pp_post(
    const float* __restrict__ p_sum,
    const float* __restrict__ W0, const float* __restrict__ W1,
    float* __restrict__ p1_new)
{
    int a = blockIdx.x * 256 + threadIdx.x;
    if (a >= N_ATOMS) return;
    const float4* src = reinterpret_cast<const float4*>(p_sum + (size_t)a * W);
    float4 v0 = src[0], v1 = src[1], v2 = src[2], v3 = src[3];
    float x[W] = {v0.x,v0.y,v0.z,v0.w, v1.x,v1.y,v1.z,v1.w,
                  v2.x,v2.y,v2.z,v2.w, v3.x,v3.y,v3.z,v3.w};
    float h[W];
#pragma unroll
    for (int c = 0; c < W; ++c) h[c] = 0.0f;
#pragma unroll
    for (int k = 0; k < W; ++k)
#pragma unroll
        for (int c = 0; c < W; ++c) h[c] += x[k] * W0[k*W + c];
#pragma unroll
    for (int c = 0; c < W; ++c) h[c] = fast_tanh(h[c]);
    float y[W];
#pragma unroll
    for (int c = 0; c < W; ++c) y[c] = 0.0f;
#pragma unroll
    for (int k = 0; k < W; ++k)
#pragma unroll
        for (int c = 0; c < W; ++c) y[c] += h[k] * W1[k*W + c];
    float4* dst = reinterpret_cast<float4*>(p1_new + (size_t)a * W);
    dst[0] = make_float4(fast_tanh(y[0]),  fast_tanh(y[1]),  fast_tanh(y[2]),  fast_tanh(y[3]));
    dst[1] = make_float4(fast_tanh(y[4]),  fast_tanh(y[5]),  fast_tanh(y[6]),  fast_tanh(y[7]));
    dst[2] = make_float4(fast_tanh(y[8]),  fast_tanh(y[9]),  fast_tanh(y[10]), fast_tanh(y[11]));
    dst[3] = make_float4(fast_tanh(y[12]), fast_tanh(y[13]), fast_tanh(y[14]), fast_tanh(y[15]));
}

extern "C" void kernel_launch(void* const* d_in, const int* in_sizes, int n_in,
                              void* d_out, int out_size, void* d_ws, size_t ws_size,
                              hipStream_t stream) {
    const int*   ind2   = (const int*)d_in[0];
    const float* p1     = (const float*)d_in[1];
    const float* basis  = (const float*)d_in[2];
    const float* Wpre0  = (const float*)d_in[3];
    const float* bpre0  = (const float*)d_in[4];
    const float* Wpre1  = (const float*)d_in[5];
    const float* bpre1  = (const float*)d_in[6];
    const float* Wpi0   = (const float*)d_in[7];
    const float* bpi0   = (const float*)d_in[8];
    const float* Wpi1   = (const float*)d_in[9];
    const float* bpi1   = (const float*)d_in[10];
    const float* Wii0   = (const float*)d_in[11];
    const float* Wii1   = (const float*)d_in[12];
    const float* Wpost0 = (const float*)d_in[13];
    const float* Wpost1 = (const float*)d_in[14];

    float* out    = (float*)d_out;
    float* p1_new = out;                          // (N_ATOMS, W)
    float* i_pair = out + (size_t)N_ATOMS * W;    // (N_PAIRS, W)

    char* ws = (char*)d_ws;
    unsigned short* p1h = (unsigned short*)ws;                    ws += (size_t)N_ATOMS * W * 2;
    unsigned short* p1l = (unsigned short*)ws;                    ws += (size_t)N_ATOMS * W * 2;
    float*    p_sum  = (float*)ws;                                ws += (size_t)N_ATOMS * W * 4;
    unsigned* counts = (unsigned*)ws;                             ws += (size_t)N_ATOMS * 4;
    unsigned* starts = (unsigned*)ws;                             ws += (size_t)N_ATOMS * 4;
    unsigned* cursor = (unsigned*)ws;                             ws += (size_t)N_ATOMS * 4;
    unsigned* bsum   = (unsigned*)ws;                             ws += 1024 * 4;
    unsigned* boff   = (unsigned*)ws;                             ws += 1024 * 4;
    float*    svals  = (float*)ws;                                ws += (size_t)N_PAIRS * W * 4;
    unsigned* rank   = (unsigned*)ws;                             ws += (size_t)N_PAIRS * 4;

    int use_rank = (ws_size >= (size_t)(ws - (char*)d_ws));

    hipMemsetAsync(counts, 0, (size_t)N_ATOMS * sizeof(unsigned), stream);
    k_pp_pre<<<(N_ATOMS + 255) / 256, 256, 0, stream>>>(p1, Wpre0, bpre0, Wpre1, bpre1, p1h, p1l);
    k_count<<<(N_PAIRS + 255) / 256, 256, 0, stream>>>(ind2, counts, use_rank ? rank : cursor);
    k_scanA<<<NB, SCAN_BLK, 0, stream>>>(counts, starts, bsum);
    k_scanB<<<1, 128, 0, stream>>>(bsum, boff);
    k_scanC<<<NB, SCAN_BLK, 0, stream>>>(starts, boff, cursor);

    if (use_rank) {
        k_pair_mfma<1><<<2560, 256, 0, stream>>>(ind2, basis, p1h, p1l,
                                                 Wpi0, bpi0, Wpi1, bpi1, Wii0, Wii1,
                                                 i_pair, starts, rank, cursor, svals);
    } else {
        k_pair_mfma<0><<<2560, 256, 0, stream>>>(ind2, basis, p1h, p1l,
                                                 Wpi0, bpi0, Wpi1, bpi1, Wii0, Wii1,
                                                 i_pair, starts, rank, cursor, svals);
    }
    k_reduce_stream<<<(N_ATOMS + 3) / 4, 256, 0, stream>>>(starts, counts, svals, p_sum);
    k_pp_post<<<(N_ATOMS + 255) / 256, 256, 0, stream>>>(p_sum, Wpost0, Wpost1, p1_new);
}